// Round 1
// baseline (346.310 us; speedup 1.0000x reference)
//
#include <hip/hip_runtime.h>
#include <hip/hip_bf16.h>

// Problem constants
#define BB   2
#define SS   2048
#define HH   2048
#define NH   32
#define NKV  8
#define HD   64
#define NTOK (BB * SS)          // 4096
#define NQKV (NH * HD + 2 * NKV * HD)  // 3072
#define KOFF (NH * HD)          // 2048 (start of K cols)
#define VOFF (NH * HD + NKV * HD)      // 2560 (start of V cols)

// Q pre-scale: 1/sqrt(HD) * log2(e), so attn can use exp2 directly
#define QSC  0.1803368801111244f

typedef short  short8  __attribute__((ext_vector_type(8)));
typedef short  short4v __attribute__((ext_vector_type(4)));
typedef float  float4v __attribute__((ext_vector_type(4)));

using bf16 = __hip_bfloat16;

#define DEV static __device__ __forceinline__

DEV short8 load8(const bf16* p) { return *(const short8*)p; }
DEV short8 load8s(const short* p) { return *(const short8*)p; }

DEV short f2bfbits(float f) {
    union { bf16 h; short s; } u;
    u.h = __float2bfloat16(f);
    return u.s;
}

DEV unsigned int packbf2(float a, float b) {
    return (unsigned int)(unsigned short)f2bfbits(a)
         | ((unsigned int)(unsigned short)f2bfbits(b) << 16);
}

// async global->LDS, 16B per lane. ldsptr must be wave-uniform; HW writes
// lane l's 16 bytes at ldsptr + l*16.
DEV void async16(const bf16* g, short* l) {
    __builtin_amdgcn_global_load_lds(
        (const __attribute__((address_space(1))) unsigned int*)g,
        (__attribute__((address_space(3))) unsigned int*)l, 16, 0, 0);
}

// ---------------- fp32 -> bf16 convert, all tensors in ONE launch ----------
__global__ __launch_bounds__(256) void cvt_all_kernel(
    const float* __restrict__ hidden, const float* __restrict__ q_w,
    const float* __restrict__ k_w, const float* __restrict__ v_w,
    const float* __restrict__ o_w,
    bf16* __restrict__ Hb, bf16* __restrict__ Wqkv, bf16* __restrict__ Wo) {
    int blk = blockIdx.x;
    const float* src;
    bf16* dst;
    int off;
    if (blk < 8192)       { src = hidden; dst = Hb;   off = blk * 1024; }
    else if (blk < 12288) { src = q_w; dst = Wqkv;    off = (blk - 8192) * 1024; }
    else if (blk < 13312) { src = k_w; dst = Wqkv + (size_t)KOFF * HH; off = (blk - 12288) * 1024; }
    else if (blk < 14336) { src = v_w; dst = Wqkv + (size_t)VOFF * HH; off = (blk - 13312) * 1024; }
    else                  { src = o_w; dst = Wo;      off = (blk - 14336) * 1024; }
    int i = off + threadIdx.x * 4;
    float4 v = *(const float4*)(src + i);
    short4v o;
    o[0] = f2bfbits(v.x); o[1] = f2bfbits(v.y);
    o[2] = f2bfbits(v.z); o[3] = f2bfbits(v.w);
    *(short4v*)(dst + i) = o;
}
#define CVT_BLOCKS 18432

// ======================= 8-phase 256-wide GEMM core =========================
// C[m][n] = sum_k A[m][k] * Bw[n][k], both row-major K-contiguous, bf16.
// BM=256, BN=NFN*64 (256 or 128), BK=64. 512 threads = 8 waves (2m x 4n).
// Per wave: 8 m-frags x NFN n-frags of 16x16, K-tile = 2 k-subs -> 64 (32)
// MFMA per K-tile, split into 4 phases of one C-quadrant each.
//
// Schedule (T3+T4+T5): per phase {ds_read subtile || stage 1 half-tile via
// global_load_lds -> barrier -> lgkmcnt(0) -> setprio(1) 16 MFMA setprio(0)
// -> barrier}. vmcnt(VN) ONLY once per K-tile (end of phase 3): 3 half-tiles
// always in flight across barriers. Staging runs 7 half-tiles ahead of
// consumption; overwrite deadlines (B-lo by end of phase0, B-hi p1, A-lo p2,
// A-hi p3) are met because ALL B frags + A m0..3 are register-read in phase
// 0 and A m4..7 in phase 1, and every wave drains lgkmcnt(0) before its
// end-of-phase barrier.
//
// LDS XOR swizzle (zero bank conflicts, carried over from the verified v7):
// physical 16B chunk = logical chunk ^ (row&7); applied on the GLOBAL source
// address at staging (LDS dest stays linear for global_load_lds) and on the
// ds_read offset (rule #21: both sides or neither).

#define QUAD(mh, nh) \
    { _Pragma("unroll") \
      for (int kh = 0; kh < 2; ++kh) { \
        _Pragma("unroll") \
        for (int mi = 0; mi < 4; ++mi) { \
          _Pragma("unroll") \
          for (int nq = 0; nq < NFN / 2; ++nq) \
            acc[(mh) * 4 + mi][(nh) * (NFN / 2) + nq] = \
                __builtin_amdgcn_mfma_f32_16x16x32_bf16( \
                    afr[(mh) * 4 + mi][kh], bfr[(nh) * (NFN / 2) + nq][kh], \
                    acc[(mh) * 4 + mi][(nh) * (NFN / 2) + nq], 0, 0, 0); } } }

#define STA(buf, r0, kt) async16(gA + (size_t)(r0) * K + (kt) * 64, lA + (buf) * ASZ + (r0) * 64)
#define STB(buf, r0, kt) async16(gB + (size_t)(r0) * K + (kt) * 64, lB + (buf) * BSZ + (r0) * 64)

template<int NFN, int K>
DEV void gemm8_loop(const bf16* __restrict__ A, const bf16* __restrict__ Bw,
                    int m0, int n0, short* sA, short* sB,
                    float4v (&acc)[8][NFN]) {
    constexpr int NT    = K / 64;       // K-tiles (>= 2)
    constexpr int ASZ   = 256 * 64;     // shorts per A buffer
    constexpr int BROWS = NFN * 64;
    constexpr int BSZ   = BROWS * 64;
    constexpr int VN    = (NFN == 4) ? 6 : 4;  // steady-state vmcnt

    const int lane = threadIdx.x & 63, w = threadIdx.x >> 6;
    const int quad = lane >> 4, tq = lane & 15;
    const int wm = w >> 2, wn = w & 3;
    const int srow = lane >> 3;                 // row within 8-row DMA group
    const int schunk = (lane & 7) ^ srow;       // pre-swizzled global chunk

    const bf16* gA = A  + (size_t)(m0 + w * 8 + srow) * K + schunk * 8;
    const bf16* gB = Bw + (size_t)(n0 + w * 8 + srow) * K + schunk * 8;
    short* lA = sA + w * 8 * 64;                // wave-uniform LDS bases
    short* lB = sB + w * 8 * 64;

    // ---- prologue: tile0 complete + tile1 minus A-hi (7 half-tiles) ----
    STB(0, 0, 0);          if (NFN == 4) STB(0, 64, 0);
    STB(0, BROWS / 2, 0);  if (NFN == 4) STB(0, BROWS / 2 + 64, 0);
    STA(0, 0, 0);   STA(0, 64, 0);
    STA(0, 128, 0); STA(0, 192, 0);
    STB(1, 0, 1);          if (NFN == 4) STB(1, 64, 1);
    STB(1, BROWS / 2, 1);  if (NFN == 4) STB(1, BROWS / 2 + 64, 1);
    STA(1, 0, 1);   STA(1, 64, 1);
    asm volatile("s_waitcnt vmcnt(%0)" :: "i"(VN) : "memory");  // tile0 landed
    __builtin_amdgcn_s_barrier();

    const int p0 = (quad ^ (tq & 7)) * 8;       // swizzled chunk offset

    for (int t = 0; t < NT; ++t) {
        const int buf = t & 1;
        const short* rA = sA + buf * ASZ + (wm * 128 + tq) * 64;
        const short* rB = sB + buf * BSZ + (wn * (NFN * 16) + tq) * 64;
        short8 afr[8][2];
        short8 bfr[NFN][2];
        const bool st1 = (t + 1 < NT);
        const bool st2 = (t + 2 < NT);

        // -------- phase 0: quadrant (m0..3, n-lo) --------
#pragma unroll
        for (int mi = 0; mi < 4; ++mi) {
            afr[mi][0] = load8s(rA + mi * 16 * 64 + p0);
            afr[mi][1] = load8s(rA + mi * 16 * 64 + (p0 ^ 32));
        }
#pragma unroll
        for (int nj = 0; nj < NFN; ++nj) {
            bfr[nj][0] = load8s(rB + nj * 16 * 64 + p0);
            bfr[nj][1] = load8s(rB + nj * 16 * 64 + (p0 ^ 32));
        }
        if (st1) { STA((t + 1) & 1, 128, t + 1); STA((t + 1) & 1, 192, t + 1); }
        __builtin_amdgcn_s_barrier();
        asm volatile("s_waitcnt lgkmcnt(0)" ::: "memory");
        __builtin_amdgcn_sched_barrier(0);
        __builtin_amdgcn_s_setprio(1);
        QUAD(0, 0);
        __builtin_amdgcn_s_setprio(0);
        __builtin_amdgcn_s_barrier();

        // -------- phase 1: quadrant (m0..3, n-hi) --------
#pragma unroll
        for (int mi = 4; mi < 8; ++mi) {
            afr[mi][0] = load8s(rA + mi * 16 * 64 + p0);
            afr[mi][1] = load8s(rA + mi * 16 * 64 + (p0 ^ 32));
        }
        if (st2) { STB(buf, 0, t + 2); if (NFN == 4) STB(buf, 64, t + 2); }
        __builtin_amdgcn_s_barrier();
        asm volatile("s_waitcnt lgkmcnt(0)" ::: "memory");
        __builtin_amdgcn_sched_barrier(0);
        __builtin_amdgcn_s_setprio(1);
        QUAD(0, 1);
        __builtin_amdgcn_s_setprio(0);
        __builtin_amdgcn_s_barrier();

        // -------- phase 2: quadrant (m4..7, n-lo) --------
        if (st2) { STB(buf, BROWS / 2, t + 2); if (NFN == 4) STB(buf, BROWS / 2 + 64, t + 2); }
        __builtin_amdgcn_s_barrier();
        asm volatile("s_waitcnt lgkmcnt(0)" ::: "memory");
        __builtin_amdgcn_sched_barrier(0);
        __builtin_amdgcn_s_setprio(1);
        QUAD(1, 0);
        __builtin_amdgcn_s_setprio(0);
        __builtin_amdgcn_s_barrier();

        // -------- phase 3: quadrant (m4..7, n-hi) + counted vmcnt --------
        if (st2) { STA(buf, 0, t + 2); STA(buf, 64, t + 2); }
        __builtin_amdgcn_s_barrier();
        asm volatile("s_waitcnt lgkmcnt(0)" ::: "memory");
        __builtin_amdgcn_sched_barrier(0);
        __builtin_amdgcn_s_setprio(1);
        QUAD(1, 1);
        __builtin_amdgcn_s_setprio(0);
        if (st2) asm volatile("s_waitcnt vmcnt(%0)" :: "i"(VN) : "memory");
        else     asm volatile("s_waitcnt vmcnt(0)" ::: "memory");
        __builtin_amdgcn_s_barrier();
    }
}

// ---------------- QKV projection + bias + RoPE (256x256 tile) --------------
__global__ __launch_bounds__(512, 2) void qkv8_kernel(
    const bf16* __restrict__ Hb, const bf16* __restrict__ Wqkv,
    const float* __restrict__ qbias, const float* __restrict__ kbias,
    const float* __restrict__ vbias,
    const float* __restrict__ cosp, const float* __restrict__ sinp,
    const int* __restrict__ posp,
    bf16* __restrict__ Qb, bf16* __restrict__ Kb, bf16* __restrict__ Vt) {
    __shared__ __align__(16) short sA[2 * 256 * 64];   // 64 KiB
    __shared__ __align__(16) short sB[2 * 256 * 64];   // 64 KiB

    // bijective XCD swizzle: 192 blocks, 24 consecutive tiles per XCD
    constexpr int NBN = NQKV / 256;                    // 12
    int flat = blockIdx.x;
    int wg = (flat & 7) * 24 + (flat >> 3);
    int bm = wg / NBN, bn = wg - bm * NBN;
    int m0 = bm * 256, n0 = bn * 256;

    float4v acc[8][4] = {};
    gemm8_loop<4, HH>(Hb, Wqkv, m0, n0, sA, sB, acc);

    int lane = threadIdx.x & 63, w = threadIdx.x >> 6;
    int quad = lane >> 4, tq = lane & 15;
    int wm = w >> 2, wn = w & 3;

    float biasv[4];
#pragma unroll
    for (int nj = 0; nj < 4; ++nj) {
        int colg = n0 + wn * 64 + nj * 16 + tq;
        biasv[nj] = (colg < KOFF) ? qbias[colg]
                  : (colg < VOFF) ? kbias[colg - KOFF] : vbias[colg - VOFF];
    }

#pragma unroll
    for (int mi = 0; mi < 8; ++mi) {
#pragma unroll
        for (int r = 0; r < 4; ++r) {
            int tok = m0 + wm * 128 + mi * 16 + quad * 4 + r;
            int p = posp[tok];
#pragma unroll
            for (int nj = 0; nj < 4; ++nj) {
                int colg = n0 + wn * 64 + nj * 16 + tq;
                float val = acc[mi][nj][r] + biasv[nj];
                if (colg < VOFF) {
                    float pv = __shfl_xor(val, 1);
                    int jh = colg & 63;
                    float Cv = cosp[p * 32 + (jh & 31)];
                    float Sv = sinp[p * 32 + (jh & 31)];
                    float outv = (jh & 1) ? (val * Cv + pv * Sv)
                                          : (val * Cv - pv * Sv);
                    if (colg < KOFF)
                        // Q pre-scaled by 1/sqrt(HD)*log2e for exp2-softmax
                        Qb[(size_t)tok * (NH * HD) + colg] = __float2bfloat16(outv * QSC);
                    else
                        Kb[(size_t)tok * (NKV * HD) + (colg - KOFF)] = __float2bfloat16(outv);
                } else {
                    int c2 = colg - VOFF;
                    int kv = c2 >> 6, d = c2 & 63;
                    int bb = tok >> 11, s = tok & (SS - 1);
                    Vt[(((size_t)bb * NKV + kv) * HD + d) * SS + s] = __float2bfloat16(val);
                }
            }
        }
    }
}

// ---------------- output projection (256x128 tile -> 256 blocks) ----------
__global__ __launch_bounds__(512, 2) void oproj8_kernel(
    const bf16* __restrict__ AO, const bf16* __restrict__ Wo,
    float* __restrict__ out) {
    __shared__ __align__(16) short sA[2 * 256 * 64];   // 64 KiB
    __shared__ __align__(16) short sB[2 * 128 * 64];   // 32 KiB

    int flat = blockIdx.x;                 // 256 blocks, 32 per XCD
    int wg = (flat & 7) * 32 + (flat >> 3);
    int bm = wg >> 4, bn = wg & 15;
    int m0 = bm * 256, n0 = bn * 128;

    float4v acc[8][2] = {};
    gemm8_loop<2, NH * HD>(AO, Wo, m0, n0, sA, sB, acc);

    int lane = threadIdx.x & 63, w = threadIdx.x >> 6;
    int quad = lane >> 4, tq = lane & 15;
    int wm = w >> 2, wn = w & 3;

#pragma unroll
    for (int mi = 0; mi < 8; ++mi) {
#pragma unroll
        for (int nj = 0; nj < 2; ++nj) {
            int colg = n0 + wn * 32 + nj * 16 + tq;
#pragma unroll
            for (int r = 0; r < 4; ++r) {
                int tok = m0 + wm * 128 + mi * 16 + quad * 4 + r;
                out[(size_t)tok * HH + colg] = acc[mi][nj][r];
            }
        }
    }
}

// ---------------- flash attention v7: 32 q-rows per wave --------------------
// (unchanged from the verified best kernel)
#define PST 72   // P-tile LDS row stride in shorts

template<bool MASK>
DEV void attn_kv_step(int kv0, int qw0, int qw1, int w, int lane, int quad, int tq,
                      const bf16* __restrict__ Kg, const bf16* __restrict__ Vg,
                      short* Ks, short* Vs, short* myp,
                      const short8 (&aq)[2][2], float4v (&ot)[4][2], float (&ls)[2]) {
    int srow = lane >> 3;                       // row within 8-row DMA group
    int schunk = (lane & 7) ^ srow;             // swizzled 16B-chunk index

    __syncthreads();   // prior step's LDS reads complete before overwrite
#pragma unroll
    for (int cc = 0; cc < 2; ++cc) {
        int rl = w * 16 + cc * 8;               // wave-uniform row base
        async16(Kg + (size_t)(kv0 + rl + srow) * (NKV * HD) + schunk * 8,
                Ks + rl * 64);
        async16(Vg + (size_t)(rl + srow) * SS + kv0 + schunk * 8,
                Vs + rl * 64);
    }
    __syncthreads();   // vmcnt drain: all 16 KB staged

    int p0 = (quad ^ (tq & 7)) * 8;             // physical chunk offset

    // ---- scores S^T for both q-chunks; exp+pack per t to cap live regs ----
#pragma unroll
    for (int t = 0; t < 4; ++t) {
        const short* kr = Ks + (t * 16 + tq) * 64;
        short8 k0 = load8s(kr + p0);
        short8 k1 = load8s(kr + (p0 ^ 32));
        float4v s0 = {0.f, 0.f, 0.f, 0.f};
        float4v s1 = {0.f, 0.f, 0.f, 0.f};
        s0 = __builtin_amdgcn_mfma_f32_16x16x32_bf16(k0, aq[0][0], s0, 0, 0, 0);
        s0 = __builtin_amdgcn_mfma_f32_16x16x32_bf16(k1, aq[0][1], s0, 0, 0, 0);
        s1 = __builtin_amdgcn_mfma_f32_16x16x32_bf16(k0, aq[1][0], s1, 0, 0, 0);
        s1 = __builtin_amdgcn_mfma_f32_16x16x32_bf16(k1, aq[1][1], s1, 0, 0, 0);
#pragma unroll
        for (int qc = 0; qc < 2; ++qc) {
            const float4v& s = qc ? s1 : s0;
            int qw = qc ? qw1 : qw0;
            float p[4];
#pragma unroll
            for (int r = 0; r < 4; ++r) {
                float e = __builtin_amdgcn_exp2f(s[r]);
                if (MASK) {
                    int kvg = kv0 + t * 16 + quad * 4 + r;
                    e = (kvg <= qw) ? e : 0.f;
                }
                p[r] = e;
                ls[qc] += e;
            }
            int pos = (qc * 16 + tq) * PST + t * 16 + quad * 4;
            *(unsigned int*)(myp + pos)     = packbf2(p[0], p[1]);
            *(unsigned int*)(myp + pos + 2) = packbf2(p[2], p[3]);
        }
    }

    // ---- read P B-frags (same-wave RAW; in-order DS pipe) ----
    short8 pf00 = load8s(myp + tq * PST + quad * 8);
    short8 pf01 = load8s(myp + tq * PST + 32 + quad * 8);
    short8 pf10 = load8s(myp + (16 + tq) * PST + quad * 8);
    short8 pf11 = load8s(myp + (16 + tq) * PST + 32 + quad * 8);

    // ---- PV: O^T[d][q] += V^T[d][kv] * P[q][kv], both q-chunks ----
#pragma unroll
    for (int i = 0; i < 4; ++i) {
        const short* vr = Vs + (i * 16 + tq) * 64;
        short8 bv0 = load8s(vr + p0);
        short8 bv1 = load8s(vr + (p0 ^ 32));
        ot[i][0] = __builtin_amdgcn_mfma_f32_16x16x32_bf16(bv0, pf00, ot[i][0], 0, 0, 0);
        ot[i][0] = __builtin_amdgcn_mfma_f32_16x16x32_bf16(bv1, pf01, ot[i][0], 0, 0, 0);
        ot[i][1] = __builtin_amdgcn_mfma_f32_16x16x32_bf16(bv0, pf10, ot[i][1], 0, 0, 0);
        ot[i][1] = __builtin_amdgcn_mfma_f32_16x16x32_bf16(bv1, pf11, ot[i][1], 0, 0, 0);
    }
}

DEV void attn_superblock(int sb, int b, int h, int w, int lane, int quad, int tq,
                         const bf16* __restrict__ Qb,
                         const bf16* __restrict__ Kg, const bf16* __restrict__ Vg,
                         short* Ks, short* Vs, short* myp, bf16* __restrict__ AO) {
    // wave w owns q rows sb + w*32 .. +31, as two 16-row chunks
    int qw0 = sb + w * 32 + tq;
    int qw1 = qw0 + 16;
    const bf16* Qr0 = Qb + (size_t)(b * SS + qw0) * (NH * HD) + h * HD + quad * 8;
    const bf16* Qr1 = Qr0 + (size_t)16 * (NH * HD);
    short8 aq[2][2];
    aq[0][0] = load8(Qr0); aq[0][1] = load8(Qr0 + 32);
    aq[1][0] = load8(Qr1); aq[1][1] = load8(Qr1 + 32);

    float4v ot[4][2] = {};
    float ls[2] = {0.f, 0.f};

    for (int kv0 = 0; kv0 < sb; kv0 += 64)
        attn_kv_step<false>(kv0, qw0, qw1, w, lane, quad, tq, Kg, Vg, Ks, Vs, myp,
                            aq, ot, ls);
    attn_kv_step<true>(sb, qw0, qw1, w, lane, quad, tq, Kg, Vg, Ks, Vs, myp,
                       aq, ot, ls);
    attn_kv_step<true>(sb + 64, qw0, qw1, w, lane, quad, tq, Kg, Vg, Ks, Vs, myp,
                       aq, ot, ls);

#pragma unroll
    for (int qc = 0; qc < 2; ++qc) {
        float lsum = ls[qc];
        lsum += __shfl_xor(lsum, 16);
        lsum += __shfl_xor(lsum, 32);
        float inv = 1.0f / lsum;
        int qg = qc ? qw1 : qw0;
        bf16* obase = AO + (size_t)(b * SS + qg) * (NH * HD) + h * HD + quad * 4;
#pragma unroll
        for (int i = 0; i < 4; ++i) {
            short4v o;
#pragma unroll
            for (int r = 0; r < 4; ++r) o[r] = f2bfbits(ot[i][qc][r] * inv);
            *(short4v*)(obase + i * 16) = o;
        }
    }
}

// grid = (64, 8), block = 256. Block processes 128-row q-superblocks
// hi=(15-jq)*128 and lo=jq*128 sequentially -> uniform 34 kv-steps.
__global__ __launch_bounds__(256, 2) void attn_kernel(
    const bf16* __restrict__ Qb, const bf16* __restrict__ Kb,
    const bf16* __restrict__ Vt, bf16* __restrict__ AO) {
    __shared__ __align__(16) short Ks[64 * 64];
    __shared__ __align__(16) short Vs[64 * 64];
    __shared__ __align__(16) short plds[4][32 * PST];

    int lane = threadIdx.x & 63, w = threadIdx.x >> 6;
    int quad = lane >> 4, tq = lane & 15;

    // XCD-aware swizzle (gridDim.x=64, XCD = flat%8 = blockIdx.x&7):
    // each XCD sees 2 (b,kvh) pairs -> ~1 MB K/V per 4 MB L2.
    int x = blockIdx.x;
    int xcd = x & 7, xi = x >> 3;
    int pair = xcd * 2 + (xi & 1);
    int b = pair >> 3, kvh = pair & 7;
    int h = kvh * 4 + (xi >> 1);

    const bf16* Kg = Kb + (size_t)(b * SS) * (NKV * HD) + kvh * HD;
    const bf16* Vg = Vt + (size_t)((b * NKV + kvh) * HD) * SS;
    short* myp = &plds[w][0];

    int jq = blockIdx.y;                 // 0..7
    attn_superblock((15 - jq) * 128, b, h, w, lane, quad, tq, Qb, Kg, Vg, Ks, Vs, myp, AO);
    attn_superblock(jq * 128,        b, h, w, lane, quad, tq, Qb, Kg, Vg, Ks, Vs, myp, AO);
}

extern "C" void kernel_launch(void* const* d_in, const int* in_sizes, int n_in,
                              void* d_out, int out_size, void* d_ws, size_t ws_size,
                              hipStream_t stream) {
    const float* hidden = (const float*)d_in[0];
    const float* cosp   = (const float*)d_in[1];
    const float* sinp   = (const float*)d_in[2];
    const int*   posp   = (const int*)d_in[3];
    // d_in[4] = mask (unused; causal mask applied analytically)
    const float* q_w = (const float*)d_in[5];
    const float* q_b = (const float*)d_in[6];
    const float* k_w = (const float*)d_in[7];
    const float* k_b = (const float*)d_in[8];
    const float* v_w = (const float*)d_in[9];
    const float* v_b = (const float*)d_in[10];
    const float* o_w = (const float*)d_in[11];
    float* out = (float*)d_out;

    char* ws = (char*)d_ws;
    bf16* Hb   = (bf16*)ws; ws += (size_t)NTOK * HH * 2;          // 16 MiB
    bf16* Wqkv = (bf16*)ws; ws += (size_t)NQKV * HH * 2;          // 12 MiB
    bf16* Wo   = (bf16*)ws; ws += (size_t)HH * (NH * HD) * 2;     // 8 MiB
    bf16* Qb   = (bf16*)ws; ws += (size_t)NTOK * (NH * HD) * 2;   // 16 MiB
    bf16* Kb   = (bf16*)ws; ws += (size_t)NTOK * (NKV * HD) * 2;  // 4 MiB
    bf16* Vt   = (bf16*)ws; ws += (size_t)NTOK * (NKV * HD) * 2;  // 4 MiB
    bf16* AO   = (bf16*)ws; ws += (size_t)NTOK * (NH * HD) * 2;   // 16 MiB

    // 1) all fp32->bf16 conversions in a single launch
    cvt_all_kernel<<<CVT_BLOCKS, 256, 0, stream>>>(
        hidden, q_w, k_w, v_w, o_w, Hb, Wqkv, Wo);

    // 2) fused QKV GEMM + bias + RoPE (+ V transpose), 8-phase 256x256
    qkv8_kernel<<<dim3(192), 512, 0, stream>>>(
        Hb, Wqkv, q_b, k_b, v_b, cosp, sinp, posp, Qb, Kb, Vt);

    // 3) flash attention (causal, GQA 4:1)
    attn_kernel<<<dim3(64, 8), 256, 0, stream>>>(Qb, Kb, Vt, AO);

    // 4) output projection -> fp32 out, 8-phase 256x128
    oproj8_kernel<<<dim3(256), 512, 0, stream>>>(AO, Wo, out);
}

// Round 2
// 296.475 us; speedup vs baseline: 1.1681x; 1.1681x over previous
//
#include <hip/hip_runtime.h>
#include <hip/hip_bf16.h>

// Problem constants
#define BB   2
#define SS   2048
#define HH   2048
#define NH   32
#define NKV  8
#define HD   64
#define NTOK (BB * SS)          // 4096
#define NQKV (NH * HD + 2 * NKV * HD)  // 3072
#define KOFF (NH * HD)          // 2048 (start of K cols)
#define VOFF (NH * HD + NKV * HD)      // 2560 (start of V cols)

// Q pre-scale: 1/sqrt(HD) * log2(e), so attn can use exp2 directly
#define QSC  0.1803368801111244f

typedef short  short8  __attribute__((ext_vector_type(8)));
typedef short  short4v __attribute__((ext_vector_type(4)));
typedef float  float4v __attribute__((ext_vector_type(4)));

using bf16 = __hip_bfloat16;

#define DEV static __device__ __forceinline__

DEV short8 load8(const bf16* p) { return *(const short8*)p; }
DEV short8 load8s(const short* p) { return *(const short8*)p; }

DEV short f2bfbits(float f) {
    union { bf16 h; short s; } u;
    u.h = __float2bfloat16(f);
    return u.s;
}

DEV unsigned int packbf2(float a, float b) {
    return (unsigned int)(unsigned short)f2bfbits(a)
         | ((unsigned int)(unsigned short)f2bfbits(b) << 16);
}

// async global->LDS, 16B per lane. ldsptr must be wave-uniform; HW writes
// lane l's 16 bytes at ldsptr + l*16.
DEV void async16(const bf16* g, short* l) {
    __builtin_amdgcn_global_load_lds(
        (const __attribute__((address_space(1))) unsigned int*)g,
        (__attribute__((address_space(3))) unsigned int*)l, 16, 0, 0);
}

// ---------------- fp32 -> bf16 convert, all tensors in ONE launch ----------
__global__ __launch_bounds__(256) void cvt_all_kernel(
    const float* __restrict__ hidden, const float* __restrict__ q_w,
    const float* __restrict__ k_w, const float* __restrict__ v_w,
    const float* __restrict__ o_w,
    bf16* __restrict__ Hb, bf16* __restrict__ Wqkv, bf16* __restrict__ Wo) {
    int blk = blockIdx.x;
    const float* src;
    bf16* dst;
    int off;
    if (blk < 8192)       { src = hidden; dst = Hb;   off = blk * 1024; }
    else if (blk < 12288) { src = q_w; dst = Wqkv;    off = (blk - 8192) * 1024; }
    else if (blk < 13312) { src = k_w; dst = Wqkv + (size_t)KOFF * HH; off = (blk - 12288) * 1024; }
    else if (blk < 14336) { src = v_w; dst = Wqkv + (size_t)VOFF * HH; off = (blk - 13312) * 1024; }
    else                  { src = o_w; dst = Wo;      off = (blk - 14336) * 1024; }
    int i = off + threadIdx.x * 4;
    float4 v = *(const float4*)(src + i);
    short4v o;
    o[0] = f2bfbits(v.x); o[1] = f2bfbits(v.y);
    o[2] = f2bfbits(v.z); o[3] = f2bfbits(v.w);
    *(short4v*)(dst + i) = o;
}
#define CVT_BLOCKS 18432

// ---------------- 128x128 GEMM mainloop, BK=64, XOR-swizzled LDS ----------
// (verified v7 structure: 712 TF on qkv in-context; m131-m141 evidence says
// source-level pipelining on this structure is neutral, so it is unchanged.)
// C[m][n] = sum_k A[m][k] * Bw[n][k]  (both row-major, K-contiguous).
struct GemmCtx {
    const bf16 *gA, *gB;      // per-lane swizzled global base (k0 added in loop)
    short *lA, *lB;           // wave-uniform LDS staging bases
    const short *rdA, *rdB;   // per-lane frag-read row bases (no chunk offset)
    int p0;                   // swizzled chunk byte-offset for kh=0
};

DEV void gemm_setup(GemmCtx& c, const bf16* A, const bf16* Bw, int K,
                    int m0, int n0, short* As, short* Bs) {
    int lane = threadIdx.x & 63, w = threadIdx.x >> 6;
    int quad = lane >> 4, tq = lane & 15;
    int srow = lane >> 3;                  // 0..7
    int schunk = (lane & 7) ^ srow;        // swizzled 16B-chunk index
    c.gA = A  + (size_t)(m0 + w * 32 + srow) * K + schunk * 8;
    c.gB = Bw + (size_t)(n0 + w * 32 + srow) * K + schunk * 8;
    c.lA = As + (w * 32) * 64;
    c.lB = Bs + (w * 32) * 64;
    int mbase = (w >> 1) * 64, nbase = (w & 1) * 64;
    c.rdA = As + (mbase + tq) * 64;
    c.rdB = Bs + (nbase + tq) * 64;
    c.p0 = (quad ^ (tq & 7)) * 8;
}

DEV void gemm_mainloop(GemmCtx& c, int K, float4v acc[4][4]) {
    for (int k0 = 0; k0 < K; k0 += 64) {
        __syncthreads();                     // prev reads done
#pragma unroll
        for (int cc = 0; cc < 4; ++cc) {
            async16(c.gA + (size_t)cc * 8 * K + k0, c.lA + cc * 8 * 64);
            async16(c.gB + (size_t)cc * 8 * K + k0, c.lB + cc * 8 * 64);
        }
        __syncthreads();                     // vmcnt drain: 32 KB staged
#pragma unroll
        for (int kh = 0; kh < 2; ++kh) {
            int off = c.p0 ^ (kh * 32);      // XOR, not add (swizzle)
            short8 af[4], bfr[4];
#pragma unroll
            for (int mi = 0; mi < 4; ++mi) af[mi]  = load8s(c.rdA + mi * 16 * 64 + off);
#pragma unroll
            for (int nj = 0; nj < 4; ++nj) bfr[nj] = load8s(c.rdB + nj * 16 * 64 + off);
#pragma unroll
            for (int mi = 0; mi < 4; ++mi)
#pragma unroll
                for (int nj = 0; nj < 4; ++nj)
                    acc[mi][nj] = __builtin_amdgcn_mfma_f32_16x16x32_bf16(
                        af[mi], bfr[nj], acc[mi][nj], 0, 0, 0);
        }
    }
}

// ---------------- QKV projection + bias + RoPE ----------------
// 1-D grid of 768 blocks with bijective XCD swizzle (768%8==0): XCD x gets
// tiles [96x, 96x+96) in m-major order -> 4 A-panels (2 MB) reused 24x from
// that XCD's L2 instead of refetched per column-block.
__global__ __launch_bounds__(256, 3) void qkv_kernel(
    const bf16* __restrict__ Hb, const bf16* __restrict__ Wqkv,
    const float* __restrict__ qbias, const float* __restrict__ kbias,
    const float* __restrict__ vbias,
    const float* __restrict__ cosp, const float* __restrict__ sinp,
    const int* __restrict__ posp,
    bf16* __restrict__ Qb, bf16* __restrict__ Kb, bf16* __restrict__ Vt) {
    __shared__ __align__(16) short As[128 * 64];
    __shared__ __align__(16) short Bs[128 * 64];
    int lane = threadIdx.x & 63, w = threadIdx.x >> 6;
    int quad = lane >> 4, tq = lane & 15;
    int flat = blockIdx.x;
    int wg = (flat & 7) * 96 + (flat >> 3);
    int bm = wg / 24, bn = wg % 24;        // bm in [0,32), bn in [0,24)
    int m0 = bm * 128, n0 = bn * 128;
    int mbase = (w >> 1) * 64, nbase = (w & 1) * 64;

    GemmCtx c;
    gemm_setup(c, Hb, Wqkv, HH, m0, n0, As, Bs);
    float4v acc[4][4] = {};
    gemm_mainloop(c, HH, acc);

    float biasv[4];
#pragma unroll
    for (int nj = 0; nj < 4; ++nj) {
        int colg = n0 + nbase + nj * 16 + tq;
        biasv[nj] = (colg < KOFF) ? qbias[colg]
                  : (colg < VOFF) ? kbias[colg - KOFF] : vbias[colg - VOFF];
    }

#pragma unroll
    for (int mi = 0; mi < 4; ++mi) {
#pragma unroll
        for (int r = 0; r < 4; ++r) {
            int tok = m0 + mbase + mi * 16 + quad * 4 + r;
            int p = posp[tok];
#pragma unroll
            for (int nj = 0; nj < 4; ++nj) {
                int colg = n0 + nbase + nj * 16 + tq;
                float val = acc[mi][nj][r] + biasv[nj];
                if (colg < VOFF) {
                    float pv = __shfl_xor(val, 1);
                    int jh = colg & 63;
                    float Cv = cosp[p * 32 + (jh & 31)];
                    float Sv = sinp[p * 32 + (jh & 31)];
                    float outv = (jh & 1) ? (val * Cv + pv * Sv)
                                          : (val * Cv - pv * Sv);
                    if (colg < KOFF)
                        // Q pre-scaled by 1/sqrt(HD)*log2e for exp2-softmax
                        Qb[(size_t)tok * (NH * HD) + colg] = __float2bfloat16(outv * QSC);
                    else
                        Kb[(size_t)tok * (NKV * HD) + (colg - KOFF)] = __float2bfloat16(outv);
                } else {
                    int c2 = colg - VOFF;
                    int kv = c2 >> 6, d = c2 & 63;
                    int bb = tok >> 11, s = tok & (SS - 1);
                    Vt[(((size_t)bb * NKV + kv) * HD + d) * SS + s] = __float2bfloat16(val);
                }
            }
        }
    }
}

// ---------------- output projection ----------------
__global__ __launch_bounds__(256, 3) void oproj_kernel(
    const bf16* __restrict__ AO, const bf16* __restrict__ Wo,
    float* __restrict__ out) {
    __shared__ __align__(16) short As[128 * 64];
    __shared__ __align__(16) short Bs[128 * 64];
    int lane = threadIdx.x & 63, w = threadIdx.x >> 6;
    int quad = lane >> 4, tq = lane & 15;
    int flat = blockIdx.x;                 // 512 blocks, 64 per XCD
    int wg = (flat & 7) * 64 + (flat >> 3);
    int bm = wg >> 4, bn = wg & 15;        // bm in [0,32), bn in [0,16)
    int m0 = bm * 128, n0 = bn * 128;
    int mbase = (w >> 1) * 64, nbase = (w & 1) * 64;

    GemmCtx c;
    gemm_setup(c, AO, Wo, NH * HD, m0, n0, As, Bs);
    float4v acc[4][4] = {};
    gemm_mainloop(c, NH * HD, acc);

#pragma unroll
    for (int mi = 0; mi < 4; ++mi) {
#pragma unroll
        for (int nj = 0; nj < 4; ++nj) {
            int colg = n0 + nbase + nj * 16 + tq;
#pragma unroll
            for (int r = 0; r < 4; ++r) {
                int tok = m0 + mbase + mi * 16 + quad * 4 + r;
                out[(size_t)tok * HH + colg] = acc[mi][nj][r];
            }
        }
    }
}

// ---------------- flash attention v8: double-buffered K/V staging ----------
// v7 compute structure (32 q-rows/wave, swapped QK^T, exp2 softmax, XOR
// swizzle) unchanged. NEW (T3-min/T14): K/V double-buffered; next tile's
// global_load_lds issued BEFORE computing the current tile; raw s_barrier +
// counted vmcnt(4) replaces __syncthreads (which force-drains vmcnt(0)), so
// 4 loads stay in flight across each compute phase. The buffer overwritten
// by iter t+1's stage is the one whose ds_reads drained at iter t's
// lgkmcnt(0)+barrier.
#define PST  72          // P-tile LDS row stride in shorts
#define KVSZ (64 * 64)   // shorts per K or V buffer

DEV void attn_stage(int buf, int kv0, int w, int lane,
                    const bf16* __restrict__ Kg, const bf16* __restrict__ Vg,
                    short* Ks, short* Vs) {
    int srow = lane >> 3;                       // row within 8-row DMA group
    int schunk = (lane & 7) ^ srow;             // swizzled 16B-chunk index
#pragma unroll
    for (int cc = 0; cc < 2; ++cc) {
        int rl = w * 16 + cc * 8;               // wave-uniform row base
        async16(Kg + (size_t)(kv0 + rl + srow) * (NKV * HD) + schunk * 8,
                Ks + buf * KVSZ + rl * 64);
        async16(Vg + (size_t)(rl + srow) * SS + kv0 + schunk * 8,
                Vs + buf * KVSZ + rl * 64);
    }
}

template<bool MASK>
DEV void attn_compute(int kv0, int qw0, int qw1, int quad, int tq,
                      const short* __restrict__ Ks, const short* __restrict__ Vs,
                      short* myp,
                      const short8 (&aq)[2][2], float4v (&ot)[4][2], float (&ls)[2]) {
    int p0 = (quad ^ (tq & 7)) * 8;             // physical chunk offset

    // ---- scores S^T for both q-chunks; exp+pack per t to cap live regs ----
#pragma unroll
    for (int t = 0; t < 4; ++t) {
        const short* kr = Ks + (t * 16 + tq) * 64;
        short8 k0 = load8s(kr + p0);
        short8 k1 = load8s(kr + (p0 ^ 32));
        float4v s0 = {0.f, 0.f, 0.f, 0.f};
        float4v s1 = {0.f, 0.f, 0.f, 0.f};
        s0 = __builtin_amdgcn_mfma_f32_16x16x32_bf16(k0, aq[0][0], s0, 0, 0, 0);
        s0 = __builtin_amdgcn_mfma_f32_16x16x32_bf16(k1, aq[0][1], s0, 0, 0, 0);
        s1 = __builtin_amdgcn_mfma_f32_16x16x32_bf16(k0, aq[1][0], s1, 0, 0, 0);
        s1 = __builtin_amdgcn_mfma_f32_16x16x32_bf16(k1, aq[1][1], s1, 0, 0, 0);
#pragma unroll
        for (int qc = 0; qc < 2; ++qc) {
            const float4v& s = qc ? s1 : s0;
            int qw = qc ? qw1 : qw0;
            float p[4];
#pragma unroll
            for (int r = 0; r < 4; ++r) {
                float e = __builtin_amdgcn_exp2f(s[r]);
                if (MASK) {
                    int kvg = kv0 + t * 16 + quad * 4 + r;
                    e = (kvg <= qw) ? e : 0.f;
                }
                p[r] = e;
                ls[qc] += e;
            }
            int pos = (qc * 16 + tq) * PST + t * 16 + quad * 4;
            *(unsigned int*)(myp + pos)     = packbf2(p[0], p[1]);
            *(unsigned int*)(myp + pos + 2) = packbf2(p[2], p[3]);
        }
    }

    // ---- read P B-frags (same-wave RAW; in-order DS pipe) ----
    short8 pf00 = load8s(myp + tq * PST + quad * 8);
    short8 pf01 = load8s(myp + tq * PST + 32 + quad * 8);
    short8 pf10 = load8s(myp + (16 + tq) * PST + quad * 8);
    short8 pf11 = load8s(myp + (16 + tq) * PST + 32 + quad * 8);

    // ---- PV: O^T[d][q] += V^T[d][kv] * P[q][kv], both q-chunks ----
#pragma unroll
    for (int i = 0; i < 4; ++i) {
        const short* vr = Vs + (i * 16 + tq) * 64;
        short8 bv0 = load8s(vr + p0);
        short8 bv1 = load8s(vr + (p0 ^ 32));
        ot[i][0] = __builtin_amdgcn_mfma_f32_16x16x32_bf16(bv0, pf00, ot[i][0], 0, 0, 0);
        ot[i][0] = __builtin_amdgcn_mfma_f32_16x16x32_bf16(bv1, pf01, ot[i][0], 0, 0, 0);
        ot[i][1] = __builtin_amdgcn_mfma_f32_16x16x32_bf16(bv0, pf10, ot[i][1], 0, 0, 0);
        ot[i][1] = __builtin_amdgcn_mfma_f32_16x16x32_bf16(bv1, pf11, ot[i][1], 0, 0, 0);
    }
}

DEV void attn_superblock(int sb, int b, int h, int w, int lane, int quad, int tq,
                         const bf16* __restrict__ Qb,
                         const bf16* __restrict__ Kg, const bf16* __restrict__ Vg,
                         short* Ks, short* Vs, short* myp, bf16* __restrict__ AO) {
    // wave w owns q rows sb + w*32 .. +31, as two 16-row chunks
    int qw0 = sb + w * 32 + tq;
    int qw1 = qw0 + 16;
    const bf16* Qr0 = Qb + (size_t)(b * SS + qw0) * (NH * HD) + h * HD + quad * 8;
    const bf16* Qr1 = Qr0 + (size_t)16 * (NH * HD);
    short8 aq[2][2];
    aq[0][0] = load8(Qr0); aq[0][1] = load8(Qr0 + 32);
    aq[1][0] = load8(Qr1); aq[1][1] = load8(Qr1 + 32);

    float4v ot[4][2] = {};
    float ls[2] = {0.f, 0.f};

    const int n = sb / 64 + 2;                  // kv tiles: 0..sb+64 step 64
    attn_stage(0, 0, w, lane, Kg, Vg, Ks, Vs);  // prologue: tile 0 -> buf 0

    for (int i = 0; i < n; ++i) {
        int kv0 = i * 64;
        if (i + 1 < n) {
            attn_stage((i + 1) & 1, kv0 + 64, w, lane, Kg, Vg, Ks, Vs);
            asm volatile("s_waitcnt vmcnt(4)" ::: "memory");  // tile i landed
        } else {
            asm volatile("s_waitcnt vmcnt(0)" ::: "memory");
        }
        __builtin_amdgcn_s_barrier();           // tile i visible to all waves
        const short* Kc = Ks + (i & 1) * KVSZ;
        const short* Vc = Vs + (i & 1) * KVSZ;
        if (kv0 < sb)
            attn_compute<false>(kv0, qw0, qw1, quad, tq, Kc, Vc, myp, aq, ot, ls);
        else
            attn_compute<true>(kv0, qw0, qw1, quad, tq, Kc, Vc, myp, aq, ot, ls);
        asm volatile("s_waitcnt lgkmcnt(0)" ::: "memory");  // LDS reads done
        __builtin_amdgcn_s_barrier();           // before next overwrite
    }

#pragma unroll
    for (int qc = 0; qc < 2; ++qc) {
        float lsum = ls[qc];
        lsum += __shfl_xor(lsum, 16);
        lsum += __shfl_xor(lsum, 32);
        float inv = 1.0f / lsum;
        int qg = qc ? qw1 : qw0;
        bf16* obase = AO + (size_t)(b * SS + qg) * (NH * HD) + h * HD + quad * 4;
#pragma unroll
        for (int i = 0; i < 4; ++i) {
            short4v o;
#pragma unroll
            for (int r = 0; r < 4; ++r) o[r] = f2bfbits(ot[i][qc][r] * inv);
            *(short4v*)(obase + i * 16) = o;
        }
    }
}

// grid = (64, 8), block = 256. Block processes 128-row q-superblocks
// hi=(15-jq)*128 and lo=jq*128 sequentially -> uniform 34 kv-steps.
__global__ __launch_bounds__(256, 2) void attn_kernel(
    const bf16* __restrict__ Qb, const bf16* __restrict__ Kb,
    const bf16* __restrict__ Vt, bf16* __restrict__ AO) {
    __shared__ __align__(16) short Ks[2 * KVSZ];
    __shared__ __align__(16) short Vs[2 * KVSZ];
    __shared__ __align__(16) short plds[4][32 * PST];

    int lane = threadIdx.x & 63, w = threadIdx.x >> 6;
    int quad = lane >> 4, tq = lane & 15;

    // XCD-aware swizzle (gridDim.x=64, XCD = flat%8 = blockIdx.x&7):
    // each XCD sees 2 (b,kvh) pairs -> ~1 MB K/V per 4 MB L2.
    int x = blockIdx.x;
    int xcd = x & 7, xi = x >> 3;
    int pair = xcd * 2 + (xi & 1);
    int b = pair >> 3, kvh = pair & 7;
    int h = kvh * 4 + (xi >> 1);

    const bf16* Kg = Kb + (size_t)(b * SS) * (NKV * HD) + kvh * HD;
    const bf16* Vg = Vt + (size_t)((b * NKV + kvh) * HD) * SS;
    short* myp = &plds[w][0];

    int jq = blockIdx.y;                 // 0..7
    attn_superblock((15 - jq) * 128, b, h, w, lane, quad, tq, Qb, Kg, Vg, Ks, Vs, myp, AO);
    attn_superblock(jq * 128,        b, h, w, lane, quad, tq, Qb, Kg, Vg, Ks, Vs, myp, AO);
}

extern "C" void kernel_launch(void* const* d_in, const int* in_sizes, int n_in,
                              void* d_out, int out_size, void* d_ws, size_t ws_size,
                              hipStream_t stream) {
    const float* hidden = (const float*)d_in[0];
    const float* cosp   = (const float*)d_in[1];
    const float* sinp   = (const float*)d_in[2];
    const int*   posp   = (const int*)d_in[3];
    // d_in[4] = mask (unused; causal mask applied analytically)
    const float* q_w = (const float*)d_in[5];
    const float* q_b = (const float*)d_in[6];
    const float* k_w = (const float*)d_in[7];
    const float* k_b = (const float*)d_in[8];
    const float* v_w = (const float*)d_in[9];
    const float* v_b = (const float*)d_in[10];
    const float* o_w = (const float*)d_in[11];
    float* out = (float*)d_out;

    char* ws = (char*)d_ws;
    bf16* Hb   = (bf16*)ws; ws += (size_t)NTOK * HH * 2;          // 16 MiB
    bf16* Wqkv = (bf16*)ws; ws += (size_t)NQKV * HH * 2;          // 12 MiB
    bf16* Wo   = (bf16*)ws; ws += (size_t)HH * (NH * HD) * 2;     // 8 MiB
    bf16* Qb   = (bf16*)ws; ws += (size_t)NTOK * (NH * HD) * 2;   // 16 MiB
    bf16* Kb   = (bf16*)ws; ws += (size_t)NTOK * (NKV * HD) * 2;  // 4 MiB
    bf16* Vt   = (bf16*)ws; ws += (size_t)NTOK * (NKV * HD) * 2;  // 4 MiB
    bf16* AO   = (bf16*)ws; ws += (size_t)NTOK * (NH * HD) * 2;   // 16 MiB

    // 1) all fp32->bf16 conversions in a single launch
    cvt_all_kernel<<<CVT_BLOCKS, 256, 0, stream>>>(
        hidden, q_w, k_w, v_w, o_w, Hb, Wqkv, Wo);

    // 2) fused QKV GEMM + bias + RoPE (+ V transpose), XCD-swizzled grid
    qkv_kernel<<<dim3(768), 256, 0, stream>>>(
        Hb, Wqkv, q_b, k_b, v_b, cosp, sinp, posp, Qb, Kb, Vt);

    // 3) flash attention (causal, GQA 4:1), double-buffered staging
    attn_kernel<<<dim3(64, 8), 256, 0, stream>>>(Qb, Kb, Vt, AO);

    // 4) output projection -> fp32 out, XCD-swizzled grid
    oproj_kernel<<<dim3(512), 256, 0, stream>>>(AO, Wo, out);
}